// Round 1
// baseline (845.362 us; speedup 1.0000x reference)
//
#include <hip/hip_runtime.h>

// ---------------------------------------------------------------------------
// DvoAm_EncTrackRefining: attention (fp32) + 3 convs as implicit GEMM (f16 MFMA,
// fp32 accum, split-K atomics) + ConvLSTM elementwise + GAP + FC.
// Shapes: B=4, C=1024, H=8, W=10 (P=80 positions), N=11 memory slots.
// ---------------------------------------------------------------------------

typedef _Float16 half8 __attribute__((ext_vector_type(8)));
typedef float f32x4 __attribute__((ext_vector_type(4)));

#define EPSF 1e-8f

__device__ __forceinline__ float sigmoidf_(float x){ return 1.0f/(1.0f+expf(-x)); }

// ---- alpha: per (n,b,p) cosine sim over channels ----
__global__ void k_alpha(const float* __restrict__ outA, const float* __restrict__ mem,
                        float* __restrict__ cs_a){
  int nb = blockIdx.x; int n = nb >> 2; int b = nb & 3;
  int p = threadIdx.x; if (p >= 80) return;
  const float* ma = mem + ((size_t)(n*4+b)*1024)*80 + p;
  const float* aa = outA + ((size_t)b*1024)*80 + p;
  float num=0.f, dm=0.f, da=0.f;
  for (int c=0;c<1024;++c){
    float m = ma[(size_t)c*80]; float a = aa[(size_t)c*80];
    num += a*m; dm += m*m; da += a*a;
  }
  float den = fmaxf(sqrtf(da)*sqrtf(dm), EPSF);
  cs_a[n*320 + b*80 + p] = num/den;
}

// ---- softmax over n=11 per (b,p) ----
__global__ void k_softmax(const float* __restrict__ cs_a, float* __restrict__ alpha){
  int t = threadIdx.x; if (t>=320) return;
  float v[11]; float mx = -1e30f;
  #pragma unroll
  for(int n=0;n<11;++n){ v[n]=cs_a[n*320+t]; mx=fmaxf(mx,v[n]); }
  float s=0.f;
  #pragma unroll
  for(int n=0;n<11;++n){ v[n]=expf(v[n]-mx); s+=v[n]; }
  float inv = 1.0f/s;
  #pragma unroll
  for(int n=0;n<11;++n) alpha[n*320+t]=v[n]*inv;
}

// ---- beta numerator/denominator: per (n,b,c) cosine over 80 spatial ----
__global__ void k_beta(const float* __restrict__ ht, const float* __restrict__ mem,
                       float* __restrict__ cs_b){
  int nb = blockIdx.x; int n = nb>>2, b = nb&3;
  for (int c = threadIdx.x; c < 1024; c += blockDim.x){
    const float4* h4 = (const float4*)(ht + ((size_t)(b*1024+c))*80);
    const float4* m4 = (const float4*)(mem + ((size_t)((n*4+b)*1024+c))*80);
    float num=0.f, dh=0.f, dm=0.f;
    #pragma unroll 4
    for(int q=0;q<20;++q){
      float4 a=h4[q], m=m4[q];
      num += a.x*m.x+a.y*m.y+a.z*m.z+a.w*m.w;
      dh  += a.x*a.x+a.y*a.y+a.z*a.z+a.w*a.w;
      dm  += m.x*m.x+m.y*m.y+m.z*m.z+m.w*m.w;
    }
    float den = fmaxf(sqrtf(dh)*sqrtf(dm), EPSF);
    cs_b[(size_t)(n*4+b)*1024 + c] = num/den;
  }
}

// ---- beta normalization over c (in place) ----
__global__ void k_betanorm(float* __restrict__ cs_b){
  int nb = blockIdx.x;
  float* base = cs_b + (size_t)nb*1024;
  int t = threadIdx.x;  // 256 threads
  float v[4]; float s=0.f;
  #pragma unroll
  for(int i=0;i<4;++i){ v[i]=base[t+256*i]; s+=v[i]; }
  for(int off=32; off; off>>=1) s += __shfl_down(s, off, 64);
  __shared__ float red[4];
  if ((t&63)==0) red[t>>6]=s;
  __syncthreads();
  float tot = red[0]+red[1]+red[2]+red[3];
  float inv = 1.0f/(tot + EPSF);
  #pragma unroll
  for(int i=0;i<4;++i) base[t+256*i] = v[i]*inv;
}

// ---- M_dash[b][c][p] = sum_n alpha * beta * mem ----
__global__ void k_mdash(const float* __restrict__ alpha, const float* __restrict__ beta,
                        const float* __restrict__ mem, float* __restrict__ md){
  int bc = blockIdx.x; int b = bc >> 10; int c = bc & 1023;
  int p = threadIdx.x; if(p>=80) return;
  float acc=0.f;
  #pragma unroll
  for(int n=0;n<11;++n){
    float al = alpha[n*320 + b*80 + p];
    float be = beta[(size_t)(n*4+b)*1024 + c];
    float m  = mem[(((size_t)(n*4+b)*1024)+c)*80 + p];
    acc += al*be*m;
  }
  md[((size_t)(b*1024)+c)*80 + p] = acc;
}

// ---- im2col: src [4][Csrc][8][10] f32 -> dst [320][Kdst] f16 at column offset ----
__global__ void k_im2col(const float* __restrict__ src, _Float16* __restrict__ dst,
                         int Kdst, int col0, int Csrc){
  int b = blockIdx.x; int cbase = blockIdx.y*16;
  for (int e = threadIdx.x; e < 16*720; e += blockDim.x){
    int p = e/144; int r = e - p*144; int cl = r/9; int tap = r - cl*9;
    int kh = tap/3, kw = tap - kh*3;
    int ph = p/10, pw = p - ph*10;
    int h = ph + kh - 1, w = pw + kw - 1;
    int c = cbase + cl;
    float v = 0.f;
    if (h>=0 && h<8 && w>=0 && w<10)
      v = src[((size_t)b*Csrc + c)*80 + h*10 + w];
    dst[((size_t)(b*80 + p))*Kdst + col0 + (size_t)c*9 + tap] = (_Float16)v;
  }
}

// ---- split-K implicit-GEMM: C[320][N] += A[320][K]_f16 * B[N][K]_f32^T ----
// Block: 64M x 64N tile, 4 waves each 32x32, MFMA 16x16x32 f16.
// k-slot assignment is OUR OWN contiguous map (grp*8+e) applied identically to A
// and B fragments => correct under any HW k-permutation (mirror-symmetric layouts).
__launch_bounds__(256)
__global__ void k_gemm(const _Float16* __restrict__ A, const float* __restrict__ B,
                       float* __restrict__ C, int N, int lda, int ldb, int ksteps){
  __shared__ __align__(16) _Float16 sA[64*32];
  __shared__ __align__(16) _Float16 sB[64*32];
  int mbase = blockIdx.x*64;
  int nbase = blockIdx.y*64;
  int kbase = blockIdx.z*ksteps*32;
  int t = threadIdx.x;
  int lane = t & 63, wv = t >> 6;
  int wm = (wv>>1)*32, wn = (wv&1)*32;
  f32x4 acc[2][2] = {};
  int row = t>>2, seg = t&3;
  const _Float16* Ap = A + (size_t)(mbase+row)*lda + kbase + seg*8;
  const float*    Bp = B + (size_t)(nbase+row)*ldb + kbase + seg*8;
  int frow = lane & 15, fgrp = lane >> 4;

  for (int ks=0; ks<ksteps; ++ks){
    half8 av = *(const half8*)(Ap);
    float4 b0 = *(const float4*)(Bp);
    float4 b1 = *(const float4*)(Bp+4);
    half8 bv;
    bv[0]=(_Float16)b0.x; bv[1]=(_Float16)b0.y; bv[2]=(_Float16)b0.z; bv[3]=(_Float16)b0.w;
    bv[4]=(_Float16)b1.x; bv[5]=(_Float16)b1.y; bv[6]=(_Float16)b1.z; bv[7]=(_Float16)b1.w;
    *(half8*)&sA[row*32 + seg*8] = av;
    *(half8*)&sB[row*32 + seg*8] = bv;
    __syncthreads();
    half8 af0 = *(const half8*)&sA[(wm      + frow)*32 + fgrp*8];
    half8 af1 = *(const half8*)&sA[(wm + 16 + frow)*32 + fgrp*8];
    half8 bf0 = *(const half8*)&sB[(wn      + frow)*32 + fgrp*8];
    half8 bf1 = *(const half8*)&sB[(wn + 16 + frow)*32 + fgrp*8];
    acc[0][0] = __builtin_amdgcn_mfma_f32_16x16x32_f16(af0, bf0, acc[0][0], 0,0,0);
    acc[0][1] = __builtin_amdgcn_mfma_f32_16x16x32_f16(af0, bf1, acc[0][1], 0,0,0);
    acc[1][0] = __builtin_amdgcn_mfma_f32_16x16x32_f16(af1, bf0, acc[1][0], 0,0,0);
    acc[1][1] = __builtin_amdgcn_mfma_f32_16x16x32_f16(af1, bf1, acc[1][1], 0,0,0);
    __syncthreads();
    Ap += 32; Bp += 32;
  }
  // C/D layout (HW-verified): n-col = lane&15, m-row = (lane>>4)*4 + reg
  #pragma unroll
  for(int i=0;i<2;++i)
    #pragma unroll
    for(int j=0;j<2;++j)
      #pragma unroll
      for(int r=0;r<4;++r){
        int m = mbase + wm + i*16 + fgrp*4 + r;
        int n = nbase + wn + j*16 + frow;
        atomicAdd(&C[(size_t)m*N + n], acc[i][j][r]);
      }
}

// ---- bias + leaky, transpose [m=b*80+p][c] -> [b][c][p] ----
__global__ void k_post(const float* __restrict__ Cacc, const float* __restrict__ bias,
                       float* __restrict__ y){
  int idx = blockIdx.x*blockDim.x + threadIdx.x;
  if (idx >= 327680) return;
  int p = idx % 80; int rest = idx/80; int c = rest & 1023; int b = rest >> 10;
  float v = Cacc[((size_t)(b*80+p))*1024 + c] + bias[c];
  y[idx] = (v >= 0.f) ? v : 0.1f*v;
}

// ---- LSTM elementwise: gates [m][4096], h0=0 so f-gate irrelevant ----
__global__ void k_lstm(const float* __restrict__ G, const float* __restrict__ bias,
                       float* __restrict__ h){
  int idx = blockIdx.x*blockDim.x + threadIdx.x;
  if (idx >= 327680) return;
  int p = idx % 80; int rest = idx/80; int c = rest & 1023; int b = rest >> 10;
  const float* g0 = G + ((size_t)(b*80+p))*4096;
  float gi = g0[c]        + bias[c];
  float go = g0[c+2048]   + bias[c+2048];
  float gg = g0[c+3072]   + bias[c+3072];
  float cc = sigmoidf_(gi)*tanhf(gg);
  h[idx] = sigmoidf_(go)*tanhf(cc);
}

// ---- global average pool over 80 ----
__global__ void k_gap(const float* __restrict__ h, float* __restrict__ gap){
  int idx = blockIdx.x*blockDim.x + threadIdx.x; if (idx>=4096) return;
  const float4* h4 = (const float4*)(h + (size_t)idx*80);
  float s=0.f;
  #pragma unroll 4
  for(int q=0;q<20;++q){ float4 v=h4[q]; s += v.x+v.y+v.z+v.w; }
  gap[idx] = s*(1.0f/80.0f);
}

// ---- final fc: out[b][j] = gap[b] . w_fc[j] + b_fc[j] ----
__global__ void k_fc(const float* __restrict__ gap, const float* __restrict__ wfc,
                     const float* __restrict__ bfc, float* __restrict__ out){
  int t = threadIdx.x; if (t >= 28) return;
  int b = t/7, j = t - b*7;
  float s = bfc[j];
  for(int c=0;c<1024;++c) s += gap[b*1024+c]*wfc[j*1024+c];
  out[t] = s;
}

extern "C" void kernel_launch(void* const* d_in, const int* in_sizes, int n_in,
                              void* d_out, int out_size, void* d_ws, size_t ws_size,
                              hipStream_t stream) {
  const float* out_enc = (const float*)d_in[0];
  const float* h_track = (const float*)d_in[1];
  const float* outA    = (const float*)d_in[2];
  const float* memory  = (const float*)d_in[3];
  const float* w1  = (const float*)d_in[4];
  const float* b1  = (const float*)d_in[5];
  const float* w2  = (const float*)d_in[6];
  const float* b2  = (const float*)d_in[7];
  const float* wl  = (const float*)d_in[8];
  const float* bl  = (const float*)d_in[9];
  const float* wfc = (const float*)d_in[10];
  const float* bfc = (const float*)d_in[11];
  float* out = (float*)d_out;

  char* ws = (char*)d_ws;
  size_t off = 0;
  auto alloc = [&](size_t bytes)->void*{
    void* p = ws + off; off += (bytes + 255) & ~(size_t)255; return p;
  };
  float* cs_a  = (float*)alloc(3520*4);
  float* alpha = (float*)alloc(3520*4);
  float* cs_b  = (float*)alloc(45056*4);          // becomes beta in place
  float* mdash = (float*)alloc(327680*4);
  float* ybuf  = (float*)alloc(327680*4);
  float* xA    = (float*)alloc(327680*4);
  float* hb    = (float*)alloc(327680*4);
  float* gap   = (float*)alloc(4096*4);
  float* Cacc  = (float*)alloc((size_t)1310720*4); // 5.24 MB, reused x3
  _Float16* Abuf = (_Float16*)alloc((size_t)5898240*2); // 11.8 MB, reused x3

  // attention
  k_alpha   <<<44, 128, 0, stream>>>(outA, memory, cs_a);
  k_softmax <<<1, 320, 0, stream>>>(cs_a, alpha);
  k_beta    <<<44, 256, 0, stream>>>(h_track, memory, cs_b);
  k_betanorm<<<44, 256, 0, stream>>>(cs_b);
  k_mdash   <<<4096, 128, 0, stream>>>(alpha, cs_b, memory, mdash);

  // conv1: temp = [out_enc | mdash], K=18432
  k_im2col<<<dim3(4,64), 256, 0, stream>>>(out_enc, Abuf, 18432, 0,    1024);
  k_im2col<<<dim3(4,64), 256, 0, stream>>>(mdash,   Abuf, 18432, 9216, 1024);
  hipMemsetAsync(Cacc, 0, (size_t)327680*4, stream);
  k_gemm<<<dim3(5,16,16), 256, 0, stream>>>(Abuf, w1, Cacc, 1024, 18432, 18432, 36);
  k_post<<<1280, 256, 0, stream>>>(Cacc, b1, ybuf);

  // conv2: K=9216
  k_im2col<<<dim3(4,64), 256, 0, stream>>>(ybuf, Abuf, 9216, 0, 1024);
  hipMemsetAsync(Cacc, 0, (size_t)327680*4, stream);
  k_gemm<<<dim3(5,16,16), 256, 0, stream>>>(Abuf, w2, Cacc, 1024, 9216, 9216, 18);
  k_post<<<1280, 256, 0, stream>>>(Cacc, b2, xA);

  // lstm conv: N=4096, only first 1024 input channels (h0=0), ldb=full 18432
  k_im2col<<<dim3(4,64), 256, 0, stream>>>(xA, Abuf, 9216, 0, 1024);
  hipMemsetAsync(Cacc, 0, (size_t)1310720*4, stream);
  k_gemm<<<dim3(5,64,8), 256, 0, stream>>>(Abuf, wl, Cacc, 4096, 9216, 18432, 36);
  k_lstm<<<1280, 256, 0, stream>>>(Cacc, bl, hb);

  // head
  k_gap<<<16, 256, 0, stream>>>(hb, gap);
  k_fc <<<1, 64, 0, stream>>>(gap, wfc, bfc, out);
}

// Round 2
// 764.922 us; speedup vs baseline: 1.1052x; 1.1052x over previous
//
#include <hip/hip_runtime.h>

// ---------------------------------------------------------------------------
// DvoAm_EncTrackRefining: attention (fp32) + 3 convs as implicit GEMM (f16 MFMA,
// fp32 accum, split-K atomics) + ConvLSTM elementwise + GAP + FC.
// Shapes: B=4, C=1024, H=8, W=10 (P=80 positions), N=11 memory slots.
// R2: weights read once (M=320 resident per block), BK=64, XOR-swizzled LDS.
// ---------------------------------------------------------------------------

typedef _Float16 half8 __attribute__((ext_vector_type(8)));
typedef float f32x4 __attribute__((ext_vector_type(4)));

#define EPSF 1e-8f

__device__ __forceinline__ float sigmoidf_(float x){ return 1.0f/(1.0f+expf(-x)); }

// ---- alpha: per (n,b,p) cosine sim over channels ----
__global__ void k_alpha(const float* __restrict__ outA, const float* __restrict__ mem,
                        float* __restrict__ cs_a){
  int nb = blockIdx.x; int n = nb >> 2; int b = nb & 3;
  int p = threadIdx.x; if (p >= 80) return;
  const float* ma = mem + ((size_t)(n*4+b)*1024)*80 + p;
  const float* aa = outA + ((size_t)b*1024)*80 + p;
  float num=0.f, dm=0.f, da=0.f;
  for (int c=0;c<1024;++c){
    float m = ma[(size_t)c*80]; float a = aa[(size_t)c*80];
    num += a*m; dm += m*m; da += a*a;
  }
  float den = fmaxf(sqrtf(da)*sqrtf(dm), EPSF);
  cs_a[n*320 + b*80 + p] = num/den;
}

// ---- softmax over n=11 per (b,p) ----
__global__ void k_softmax(const float* __restrict__ cs_a, float* __restrict__ alpha){
  int t = threadIdx.x; if (t>=320) return;
  float v[11]; float mx = -1e30f;
  #pragma unroll
  for(int n=0;n<11;++n){ v[n]=cs_a[n*320+t]; mx=fmaxf(mx,v[n]); }
  float s=0.f;
  #pragma unroll
  for(int n=0;n<11;++n){ v[n]=expf(v[n]-mx); s+=v[n]; }
  float inv = 1.0f/s;
  #pragma unroll
  for(int n=0;n<11;++n) alpha[n*320+t]=v[n]*inv;
}

// ---- beta: per (n,b,c) cosine over 80 spatial ----
__global__ void k_beta(const float* __restrict__ ht, const float* __restrict__ mem,
                       float* __restrict__ cs_b){
  int nb = blockIdx.x; int n = nb>>2, b = nb&3;
  for (int c = threadIdx.x; c < 1024; c += blockDim.x){
    const float4* h4 = (const float4*)(ht + ((size_t)(b*1024+c))*80);
    const float4* m4 = (const float4*)(mem + ((size_t)((n*4+b)*1024+c))*80);
    float num=0.f, dh=0.f, dm=0.f;
    #pragma unroll 4
    for(int q=0;q<20;++q){
      float4 a=h4[q], m=m4[q];
      num += a.x*m.x+a.y*m.y+a.z*m.z+a.w*m.w;
      dh  += a.x*a.x+a.y*a.y+a.z*a.z+a.w*a.w;
      dm  += m.x*m.x+m.y*m.y+m.z*m.z+m.w*m.w;
    }
    float den = fmaxf(sqrtf(dh)*sqrtf(dm), EPSF);
    cs_b[(size_t)(n*4+b)*1024 + c] = num/den;
  }
}

// ---- beta normalization over c (in place) ----
__global__ void k_betanorm(float* __restrict__ cs_b){
  int nb = blockIdx.x;
  float* base = cs_b + (size_t)nb*1024;
  int t = threadIdx.x;  // 256 threads
  float v[4]; float s=0.f;
  #pragma unroll
  for(int i=0;i<4;++i){ v[i]=base[t+256*i]; s+=v[i]; }
  for(int off=32; off; off>>=1) s += __shfl_down(s, off, 64);
  __shared__ float red[4];
  if ((t&63)==0) red[t>>6]=s;
  __syncthreads();
  float tot = red[0]+red[1]+red[2]+red[3];
  float inv = 1.0f/(tot + EPSF);
  #pragma unroll
  for(int i=0;i<4;++i) base[t+256*i] = v[i]*inv;
}

// ---- M_dash[b][c][p] = sum_n alpha * beta * mem ----
__global__ void k_mdash(const float* __restrict__ alpha, const float* __restrict__ beta,
                        const float* __restrict__ mem, float* __restrict__ md){
  int bc = blockIdx.x; int b = bc >> 10; int c = bc & 1023;
  int p = threadIdx.x; if(p>=80) return;
  float acc=0.f;
  #pragma unroll
  for(int n=0;n<11;++n){
    float al = alpha[n*320 + b*80 + p];
    float be = beta[(size_t)(n*4+b)*1024 + c];
    float m  = mem[(((size_t)(n*4+b)*1024)+c)*80 + p];
    acc += al*be*m;
  }
  md[((size_t)(b*1024)+c)*80 + p] = acc;
}

// ---- im2col: src [4][Csrc][8][10] f32 -> dst [320][Kdst] f16 at column offset ----
__global__ void k_im2col(const float* __restrict__ src, _Float16* __restrict__ dst,
                         int Kdst, int col0, int Csrc){
  int b = blockIdx.x; int cbase = blockIdx.y*16;
  for (int e = threadIdx.x; e < 16*720; e += blockDim.x){
    int p = e/144; int r = e - p*144; int cl = r/9; int tap = r - cl*9;
    int kh = tap/3, kw = tap - kh*3;
    int ph = p/10, pw = p - ph*10;
    int h = ph + kh - 1, w = pw + kw - 1;
    int c = cbase + cl;
    float v = 0.f;
    if (h>=0 && h<8 && w>=0 && w<10)
      v = src[((size_t)b*Csrc + c)*80 + h*10 + w];
    dst[((size_t)(b*80 + p))*Kdst + col0 + (size_t)c*9 + tap] = (_Float16)v;
  }
}

// ---- split-K implicit-GEMM v2 ----
// C[320][N] += A[320][K]_f16 * B[N][K]_f32^T
// Block owns (ntile of 64, k-chunk of hsteps*64); M=320 fully LDS-resident per
// k-step. B read exactly once grid-wide. 4 waves in 2x2 over (m32,n32) per mtile.
// LDS rows are 128B -> XOR chunk swizzle seg^(row&7) on BOTH write and read.
// k-slot packing identical for A and B fragments (mirror-symmetric layouts),
// only C/D layout (col=lane&15, row=(lane>>4)*4+reg) relied upon.
__launch_bounds__(256)
__global__ void k_gemm2(const _Float16* __restrict__ A, const float* __restrict__ B,
                        float* __restrict__ C, int N, int lda, int ldb, int hsteps){
  __shared__ __align__(16) _Float16 sA[320*64];
  __shared__ __align__(16) _Float16 sB[64*64];
  int nbase = blockIdx.x * 64;
  int kbase = blockIdx.y * hsteps * 64;
  int t = threadIdx.x;
  int lane = t & 63, wv = t >> 6;
  int wm2 = (wv >> 1), wn2 = (wv & 1);
  int frow = lane & 15, fgrp = lane >> 4;
  f32x4 acc[5][2][2] = {};

  for (int hs = 0; hs < hsteps; ++hs){
    int k = kbase + hs*64;
    // stage A: 320x64 f16 = 2560 16B-chunks, 10 per thread
    #pragma unroll
    for (int i = 0; i < 10; ++i){
      int ci = t + 256*i;
      int row = ci >> 3, seg = ci & 7;
      half8 v = *(const half8*)(A + (size_t)row*lda + k + seg*8);
      *(half8*)&sA[row*64 + ((seg ^ (row & 7))*8)] = v;
    }
    // stage B: 64x64 fp32 -> f16, 512 chunks, 2 per thread
    #pragma unroll
    for (int i = 0; i < 2; ++i){
      int ci = t + 256*i;
      int row = ci >> 3, seg = ci & 7;
      const float* bp = B + (size_t)(nbase+row)*ldb + k + seg*8;
      float4 b0 = *(const float4*)bp;
      float4 b1 = *(const float4*)(bp+4);
      half8 bv;
      bv[0]=(_Float16)b0.x; bv[1]=(_Float16)b0.y; bv[2]=(_Float16)b0.z; bv[3]=(_Float16)b0.w;
      bv[4]=(_Float16)b1.x; bv[5]=(_Float16)b1.y; bv[6]=(_Float16)b1.z; bv[7]=(_Float16)b1.w;
      *(half8*)&sB[row*64 + ((seg ^ (row & 7))*8)] = bv;
    }
    __syncthreads();

    // B fragments: [j=n16][ksub], hoisted across the 5 m-tiles
    half8 bf[2][2];
    #pragma unroll
    for (int j = 0; j < 2; ++j)
      #pragma unroll
      for (int ks = 0; ks < 2; ++ks){
        int r = wn2*32 + j*16 + frow;
        int c = fgrp + 4*ks;
        bf[j][ks] = *(const half8*)&sB[r*64 + ((c ^ (r & 7))*8)];
      }

    #pragma unroll
    for (int mt = 0; mt < 5; ++mt){
      half8 af[2][2];
      #pragma unroll
      for (int i = 0; i < 2; ++i)
        #pragma unroll
        for (int ks = 0; ks < 2; ++ks){
          int r = mt*64 + wm2*32 + i*16 + frow;
          int c = fgrp + 4*ks;
          af[i][ks] = *(const half8*)&sA[r*64 + ((c ^ (r & 7))*8)];
        }
      #pragma unroll
      for (int i = 0; i < 2; ++i)
        #pragma unroll
        for (int j = 0; j < 2; ++j){
          acc[mt][i][j] = __builtin_amdgcn_mfma_f32_16x16x32_f16(af[i][0], bf[j][0], acc[mt][i][j], 0,0,0);
          acc[mt][i][j] = __builtin_amdgcn_mfma_f32_16x16x32_f16(af[i][1], bf[j][1], acc[mt][i][j], 0,0,0);
        }
    }
    __syncthreads();
  }

  // epilogue: C/D layout col=lane&15, row=(lane>>4)*4+reg
  #pragma unroll
  for (int mt = 0; mt < 5; ++mt)
    #pragma unroll
    for (int i = 0; i < 2; ++i)
      #pragma unroll
      for (int j = 0; j < 2; ++j)
        #pragma unroll
        for (int r = 0; r < 4; ++r){
          int m = mt*64 + wm2*32 + i*16 + fgrp*4 + r;
          int n = nbase + wn2*32 + j*16 + frow;
          atomicAdd(&C[(size_t)m*N + n], acc[mt][i][j][r]);
        }
}

// ---- bias + leaky, transpose [m=b*80+p][c] -> [b][c][p] ----
__global__ void k_post(const float* __restrict__ Cacc, const float* __restrict__ bias,
                       float* __restrict__ y){
  int idx = blockIdx.x*blockDim.x + threadIdx.x;
  if (idx >= 327680) return;
  int p = idx % 80; int rest = idx/80; int c = rest & 1023; int b = rest >> 10;
  float v = Cacc[((size_t)(b*80+p))*1024 + c] + bias[c];
  y[idx] = (v >= 0.f) ? v : 0.1f*v;
}

// ---- LSTM elementwise: gates [m][4096], h0=0 so f-gate irrelevant ----
__global__ void k_lstm(const float* __restrict__ G, const float* __restrict__ bias,
                       float* __restrict__ h){
  int idx = blockIdx.x*blockDim.x + threadIdx.x;
  if (idx >= 327680) return;
  int p = idx % 80; int rest = idx/80; int c = rest & 1023; int b = rest >> 10;
  const float* g0 = G + ((size_t)(b*80+p))*4096;
  float gi = g0[c]        + bias[c];
  float go = g0[c+2048]   + bias[c+2048];
  float gg = g0[c+3072]   + bias[c+3072];
  float cc = sigmoidf_(gi)*tanhf(gg);
  h[idx] = sigmoidf_(go)*tanhf(cc);
}

// ---- global average pool over 80 ----
__global__ void k_gap(const float* __restrict__ h, float* __restrict__ gap){
  int idx = blockIdx.x*blockDim.x + threadIdx.x; if (idx>=4096) return;
  const float4* h4 = (const float4*)(h + (size_t)idx*80);
  float s=0.f;
  #pragma unroll 4
  for(int q=0;q<20;++q){ float4 v=h4[q]; s += v.x+v.y+v.z+v.w; }
  gap[idx] = s*(1.0f/80.0f);
}

// ---- final fc: out[b][j] = gap[b] . w_fc[j] + b_fc[j] ----
__global__ void k_fc(const float* __restrict__ gap, const float* __restrict__ wfc,
                     const float* __restrict__ bfc, float* __restrict__ out){
  int t = threadIdx.x; if (t >= 28) return;
  int b = t/7, j = t - b*7;
  float s = bfc[j];
  for(int c=0;c<1024;++c) s += gap[b*1024+c]*wfc[j*1024+c];
  out[t] = s;
}

extern "C" void kernel_launch(void* const* d_in, const int* in_sizes, int n_in,
                              void* d_out, int out_size, void* d_ws, size_t ws_size,
                              hipStream_t stream) {
  const float* out_enc = (const float*)d_in[0];
  const float* h_track = (const float*)d_in[1];
  const float* outA    = (const float*)d_in[2];
  const float* memory  = (const float*)d_in[3];
  const float* w1  = (const float*)d_in[4];
  const float* b1  = (const float*)d_in[5];
  const float* w2  = (const float*)d_in[6];
  const float* b2  = (const float*)d_in[7];
  const float* wl  = (const float*)d_in[8];
  const float* bl  = (const float*)d_in[9];
  const float* wfc = (const float*)d_in[10];
  const float* bfc = (const float*)d_in[11];
  float* out = (float*)d_out;

  char* ws = (char*)d_ws;
  size_t off = 0;
  auto alloc = [&](size_t bytes)->void*{
    void* p = ws + off; off += (bytes + 255) & ~(size_t)255; return p;
  };
  float* cs_a  = (float*)alloc(3520*4);
  float* alpha = (float*)alloc(3520*4);
  float* cs_b  = (float*)alloc(45056*4);          // becomes beta in place
  float* mdash = (float*)alloc(327680*4);
  float* ybuf  = (float*)alloc(327680*4);
  float* xA    = (float*)alloc(327680*4);
  float* hb    = (float*)alloc(327680*4);
  float* gap   = (float*)alloc(4096*4);
  float* Cacc  = (float*)alloc((size_t)1310720*4); // 5.24 MB, reused x3
  _Float16* Abuf = (_Float16*)alloc((size_t)5898240*2); // 11.8 MB, reused x3

  // attention
  k_alpha   <<<44, 128, 0, stream>>>(outA, memory, cs_a);
  k_softmax <<<1, 320, 0, stream>>>(cs_a, alpha);
  k_beta    <<<44, 256, 0, stream>>>(h_track, memory, cs_b);
  k_betanorm<<<44, 256, 0, stream>>>(cs_b);
  k_mdash   <<<4096, 128, 0, stream>>>(alpha, cs_b, memory, mdash);

  // conv1: temp = [out_enc | mdash], K=18432, N=1024
  k_im2col<<<dim3(4,64), 256, 0, stream>>>(out_enc, Abuf, 18432, 0,    1024);
  k_im2col<<<dim3(4,64), 256, 0, stream>>>(mdash,   Abuf, 18432, 9216, 1024);
  hipMemsetAsync(Cacc, 0, (size_t)327680*4, stream);
  k_gemm2<<<dim3(16,16), 256, 0, stream>>>(Abuf, w1, Cacc, 1024, 18432, 18432, 18);
  k_post<<<1280, 256, 0, stream>>>(Cacc, b1, ybuf);

  // conv2: K=9216, N=1024
  k_im2col<<<dim3(4,64), 256, 0, stream>>>(ybuf, Abuf, 9216, 0, 1024);
  hipMemsetAsync(Cacc, 0, (size_t)327680*4, stream);
  k_gemm2<<<dim3(16,16), 256, 0, stream>>>(Abuf, w2, Cacc, 1024, 9216, 9216, 9);
  k_post<<<1280, 256, 0, stream>>>(Cacc, b2, xA);

  // lstm conv: N=4096, only first 1024 input channels matter (h0=0), ldb=18432
  k_im2col<<<dim3(4,64), 256, 0, stream>>>(xA, Abuf, 9216, 0, 1024);
  hipMemsetAsync(Cacc, 0, (size_t)1310720*4, stream);
  k_gemm2<<<dim3(64,8), 256, 0, stream>>>(Abuf, wl, Cacc, 4096, 9216, 18432, 18);
  k_lstm<<<1280, 256, 0, stream>>>(Cacc, bl, hb);

  // head
  k_gap<<<16, 256, 0, stream>>>(hb, gap);
  k_fc <<<1, 64, 0, stream>>>(gap, wfc, bfc, out);
}

// Round 3
// 637.151 us; speedup vs baseline: 1.3268x; 1.2005x over previous
//
#include <hip/hip_runtime.h>

// ---------------------------------------------------------------------------
// DvoAm_EncTrackRefining. R3: 8-wave GEMM blocks, split-K via partial slabs
// (no atomics) with fused reduction epilogues, f-gate skipped in LSTM GEMM,
// reg-pipelined staging (T14-lite), parallelized attention.
// Shapes: B=4, C=1024, H=8, W=10 (P=80, M=320 rows), N=11 slots.
// ---------------------------------------------------------------------------

typedef _Float16 half8 __attribute__((ext_vector_type(8)));
typedef float f32x4 __attribute__((ext_vector_type(4)));

#define EPSF 1e-8f

__device__ __forceinline__ float sigmoidf_(float x){ return 1.0f/(1.0f+expf(-x)); }

// ---- alpha partials: per (n,b,p) over a 128-channel slice ----
__global__ void k_alpha_part(const float* __restrict__ outA, const float* __restrict__ mem,
                             float* __restrict__ numg, float* __restrict__ dmg,
                             float* __restrict__ dag){
  int nb = blockIdx.x; int n = nb >> 2; int b = nb & 3;
  int c0 = blockIdx.y * 128;
  int p = threadIdx.x; if (p >= 80) return;
  const float* ma = mem + ((size_t)((n*4+b)*1024 + c0))*80 + p;
  const float* aa = outA + ((size_t)(b*1024 + c0))*80 + p;
  float num=0.f, dm=0.f, da=0.f;
  #pragma unroll 8
  for (int c=0;c<128;++c){
    float m = ma[(size_t)c*80]; float a = aa[(size_t)c*80];
    num += a*m; dm += m*m; da += a*a;
  }
  atomicAdd(&numg[n*320 + b*80 + p], num);
  atomicAdd(&dmg [n*320 + b*80 + p], dm);
  if (n == 0) atomicAdd(&dag[b*80 + p], da);
}

// ---- cs + softmax over n=11 per (b,p) ----
__global__ void k_cs_soft(const float* __restrict__ numg, const float* __restrict__ dmg,
                          const float* __restrict__ dag, float* __restrict__ alpha){
  int t = threadIdx.x; if (t>=320) return;
  float sda = sqrtf(dag[t]);
  float v[11]; float mx = -1e30f;
  #pragma unroll
  for(int n=0;n<11;++n){
    float cs = numg[n*320+t] / fmaxf(sda*sqrtf(dmg[n*320+t]), EPSF);
    v[n]=cs; mx=fmaxf(mx,cs);
  }
  float s=0.f;
  #pragma unroll
  for(int n=0;n<11;++n){ v[n]=expf(v[n]-mx); s+=v[n]; }
  float inv = 1.0f/s;
  #pragma unroll
  for(int n=0;n<11;++n) alpha[n*320+t]=v[n]*inv;
}

// ---- beta: per (n,b,c) cosine over 80 spatial, fused normalization over c ----
__global__ void k_beta_f(const float* __restrict__ ht, const float* __restrict__ mem,
                         float* __restrict__ beta){
  int nb = blockIdx.x; int n = nb>>2, b = nb&3;
  int t = threadIdx.x;  // 256
  float v[4]; float s=0.f;
  #pragma unroll
  for (int i=0;i<4;++i){
    int c = t + 256*i;
    const float4* h4 = (const float4*)(ht + ((size_t)(b*1024+c))*80);
    const float4* m4 = (const float4*)(mem + ((size_t)((n*4+b)*1024+c))*80);
    float num=0.f, dh=0.f, dm=0.f;
    #pragma unroll 4
    for(int q=0;q<20;++q){
      float4 a=h4[q], m=m4[q];
      num += a.x*m.x+a.y*m.y+a.z*m.z+a.w*m.w;
      dh  += a.x*a.x+a.y*a.y+a.z*a.z+a.w*a.w;
      dm  += m.x*m.x+m.y*m.y+m.z*m.z+m.w*m.w;
    }
    v[i] = num / fmaxf(sqrtf(dh)*sqrtf(dm), EPSF);
    s += v[i];
  }
  for (int off=32; off; off>>=1) s += __shfl_down(s, off, 64);
  __shared__ float red[4];
  if ((t&63)==0) red[t>>6]=s;
  __syncthreads();
  float inv = 1.0f/(red[0]+red[1]+red[2]+red[3] + EPSF);
  #pragma unroll
  for (int i=0;i<4;++i) beta[(size_t)nb*1024 + t + 256*i] = v[i]*inv;
}

// ---- M_dash[b][c][p] = sum_n alpha * beta * mem ----
__global__ void k_mdash(const float* __restrict__ alpha, const float* __restrict__ beta,
                        const float* __restrict__ mem, float* __restrict__ md){
  int bc = blockIdx.x; int b = bc >> 10; int c = bc & 1023;
  int p = threadIdx.x; if(p>=80) return;
  float acc=0.f;
  #pragma unroll
  for(int n=0;n<11;++n){
    float al = alpha[n*320 + b*80 + p];
    float be = beta[(size_t)(n*4+b)*1024 + c];
    float m  = mem[(((size_t)(n*4+b)*1024)+c)*80 + p];
    acc += al*be*m;
  }
  md[((size_t)(b*1024)+c)*80 + p] = acc;
}

// ---- im2col: src [4][1024][8][10] f32 -> dst [320][Kdst] f16 at column offset ----
__global__ void k_im2col(const float* __restrict__ src, _Float16* __restrict__ dst,
                         int Kdst, int col0, int Csrc){
  int b = blockIdx.x; int cbase = blockIdx.y*16;
  for (int e = threadIdx.x; e < 16*720; e += blockDim.x){
    int p = e/144; int r = e - p*144; int cl = r/9; int tap = r - cl*9;
    int kh = tap/3, kw = tap - kh*3;
    int ph = p/10, pw = p - ph*10;
    int h = ph + kh - 1, w = pw + kw - 1;
    int c = cbase + cl;
    float v = 0.f;
    if (h>=0 && h<8 && w>=0 && w<10)
      v = src[((size_t)b*Csrc + c)*80 + h*10 + w];
    dst[((size_t)(b*80 + p))*Kdst + col0 + (size_t)c*9 + tap] = (_Float16)v;
  }
}

// ---- split-K implicit-GEMM v3 ----
// Cpart[split][320][ncols] = A[320][K]_f16 * B[N][K]_f32^T  (per k-chunk partial)
// 512 threads = 8 waves in 2m x 4n over the 64-wide n-tile; M=320 LDS-resident.
// XOR chunk swizzle seg^(row&7) on both LDS write and read (128B rows).
// k-slot packing identical for A and B frags (mirror symmetry); C/D layout
// col=lane&15, row=(lane>>4)*4+reg (HW-verified).
// nskip: lstm skips the unused f-gate n-tiles (B cols), Cpart stays dense.
__launch_bounds__(512)
__global__ void k_gemm3(const _Float16* __restrict__ A, const float* __restrict__ B,
                        float* __restrict__ Cp, int ncols, int lda, int ldb,
                        int hsteps, int nskip_at, int nskip){
  __shared__ __align__(16) _Float16 sA[320*64];
  __shared__ __align__(16) _Float16 sB[64*64];
  int ntl = blockIdx.x;
  int nt  = (ntl < nskip_at) ? ntl : ntl + nskip;
  int col0 = ntl*64;
  int kbase = blockIdx.y*hsteps*64;
  int t = threadIdx.x;
  int lane = t & 63, wv = t >> 6;
  int wm2 = wv >> 2, wn2 = wv & 3;      // 2 x 4 waves
  int frow = lane & 15, fgrp = lane >> 4;
  f32x4 acc[5][2] = {};

  const _Float16* Ab = A + kbase;
  const float*    Bb = B + (size_t)(nt*64)*ldb + kbase;
  int arow[5], aseg[5];
  #pragma unroll
  for (int i=0;i<5;++i){ int ci = t + 512*i; arow[i]=ci>>3; aseg[i]=ci&7; }
  int brow = t>>3, bseg = t&7;

  // preload hs=0
  half8 ra[5]; float4 rb0, rb1;
  #pragma unroll
  for (int i=0;i<5;++i) ra[i] = *(const half8*)(Ab + (size_t)arow[i]*lda + aseg[i]*8);
  { const float* bp = Bb + (size_t)brow*ldb + bseg*8;
    rb0 = *(const float4*)bp; rb1 = *(const float4*)(bp+4); }

  for (int hs=0; hs<hsteps; ++hs){
    // issue next-step loads first (latency hides under ds_write+MFMA phases)
    half8 na[5]; float4 nb0, nb1;
    if (hs+1 < hsteps){
      const _Float16* A2 = Ab + (hs+1)*64;
      const float*    B2 = Bb + (hs+1)*64;
      #pragma unroll
      for (int i=0;i<5;++i) na[i] = *(const half8*)(A2 + (size_t)arow[i]*lda + aseg[i]*8);
      const float* bp = B2 + (size_t)brow*ldb + bseg*8;
      nb0 = *(const float4*)bp; nb1 = *(const float4*)(bp+4);
    }
    // stage current into LDS (swizzled)
    #pragma unroll
    for (int i=0;i<5;++i)
      *(half8*)&sA[arow[i]*64 + ((aseg[i] ^ (arow[i]&7))*8)] = ra[i];
    {
      half8 bv;
      bv[0]=(_Float16)rb0.x; bv[1]=(_Float16)rb0.y; bv[2]=(_Float16)rb0.z; bv[3]=(_Float16)rb0.w;
      bv[4]=(_Float16)rb1.x; bv[5]=(_Float16)rb1.y; bv[6]=(_Float16)rb1.z; bv[7]=(_Float16)rb1.w;
      *(half8*)&sB[brow*64 + ((bseg ^ (brow&7))*8)] = bv;
    }
    __syncthreads();

    half8 bf[2];
    #pragma unroll
    for (int ks=0; ks<2; ++ks){
      int r = wn2*16 + frow;
      int c = fgrp + 4*ks;
      bf[ks] = *(const half8*)&sB[r*64 + ((c ^ (r&7))*8)];
    }
    #pragma unroll
    for (int mt=0; mt<5; ++mt){
      half8 af[2][2];
      #pragma unroll
      for (int i=0;i<2;++i)
        #pragma unroll
        for (int ks=0;ks<2;++ks){
          int r = mt*64 + wm2*32 + i*16 + frow;
          int c = fgrp + 4*ks;
          af[i][ks] = *(const half8*)&sA[r*64 + ((c ^ (r&7))*8)];
        }
      #pragma unroll
      for (int i=0;i<2;++i){
        acc[mt][i] = __builtin_amdgcn_mfma_f32_16x16x32_f16(af[i][0], bf[0], acc[mt][i],0,0,0);
        acc[mt][i] = __builtin_amdgcn_mfma_f32_16x16x32_f16(af[i][1], bf[1], acc[mt][i],0,0,0);
      }
    }
    __syncthreads();
    #pragma unroll
    for (int i=0;i<5;++i) ra[i]=na[i];
    rb0=nb0; rb1=nb1;
  }

  float* Cw = Cp + (size_t)blockIdx.y*320*ncols;
  #pragma unroll
  for (int mt=0;mt<5;++mt)
    #pragma unroll
    for (int i=0;i<2;++i)
      #pragma unroll
      for (int r=0;r<4;++r){
        int m = mt*64 + wm2*32 + i*16 + fgrp*4 + r;
        int n = col0 + wn2*16 + frow;
        Cw[(size_t)m*ncols + n] = acc[mt][i][r];
      }
}

// ---- split-reduce + bias + leaky, transpose [m][c] -> [b][c][p] ----
__global__ void k_post_red(const float* __restrict__ Cp, int splits,
                           const float* __restrict__ bias, float* __restrict__ y){
  int tid = blockIdx.x*256 + threadIdx.x; if (tid >= 327680) return;
  int m = tid >> 10, c = tid & 1023;
  float s = bias[c];
  for (int sp=0; sp<splits; ++sp) s += Cp[(size_t)sp*327680 + tid];
  s = (s >= 0.f) ? s : 0.1f*s;
  int b = m/80, p = m - (m/80)*80;
  y[((size_t)(b*1024)+c)*80 + p] = s;
}

// ---- split-reduce + LSTM elementwise (dense cols: [i|o|g] of 1024 each) ----
__global__ void k_lstm_red(const float* __restrict__ Cp, const float* __restrict__ bias,
                           float* __restrict__ h){
  int tid = blockIdx.x*256 + threadIdx.x; if (tid >= 327680) return;
  int m = tid >> 10, c = tid & 1023;
  float gi = bias[c], go = bias[2048+c], gg = bias[3072+c];
  const float* base = Cp + (size_t)m*3072 + c;
  #pragma unroll
  for (int sp=0; sp<8; ++sp){
    const float* bp = base + (size_t)sp*983040;
    gi += bp[0]; go += bp[1024]; gg += bp[2048];
  }
  float cc = sigmoidf_(gi)*tanhf(gg);
  int b = m/80, p = m - (m/80)*80;
  h[((size_t)(b*1024)+c)*80 + p] = sigmoidf_(go)*tanhf(cc);
}

// ---- global average pool over 80 ----
__global__ void k_gap(const float* __restrict__ h, float* __restrict__ gap){
  int idx = blockIdx.x*blockDim.x + threadIdx.x; if (idx>=4096) return;
  const float4* h4 = (const float4*)(h + (size_t)idx*80);
  float s=0.f;
  #pragma unroll 4
  for(int q=0;q<20;++q){ float4 v=h4[q]; s += v.x+v.y+v.z+v.w; }
  gap[idx] = s*(1.0f/80.0f);
}

// ---- final fc: wave-per-(b,j) pair, butterfly reduce ----
__global__ void k_fc(const float* __restrict__ gap, const float* __restrict__ wfc,
                     const float* __restrict__ bfc, float* __restrict__ out){
  int wv = threadIdx.x >> 6, lane = threadIdx.x & 63;
  for (int pair = wv; pair < 28; pair += 8){
    int b = pair/7, j = pair - (pair/7)*7;
    const float4* g4 = (const float4*)(gap + b*1024);
    const float4* w4 = (const float4*)(wfc + j*1024);
    float s = 0.f;
    #pragma unroll
    for (int i=0;i<4;++i){
      float4 g = g4[lane + 64*i], w = w4[lane + 64*i];
      s += g.x*w.x + g.y*w.y + g.z*w.z + g.w*w.w;
    }
    for (int off=32; off; off>>=1) s += __shfl_down(s, off, 64);
    if (lane==0) out[pair] = s + bfc[j];
  }
}

extern "C" void kernel_launch(void* const* d_in, const int* in_sizes, int n_in,
                              void* d_out, int out_size, void* d_ws, size_t ws_size,
                              hipStream_t stream) {
  const float* out_enc = (const float*)d_in[0];
  const float* h_track = (const float*)d_in[1];
  const float* outA    = (const float*)d_in[2];
  const float* memory  = (const float*)d_in[3];
  const float* w1  = (const float*)d_in[4];
  const float* b1  = (const float*)d_in[5];
  const float* w2  = (const float*)d_in[6];
  const float* b2  = (const float*)d_in[7];
  const float* wl  = (const float*)d_in[8];
  const float* bl  = (const float*)d_in[9];
  const float* wfc = (const float*)d_in[10];
  const float* bfc = (const float*)d_in[11];
  float* out = (float*)d_out;

  char* ws = (char*)d_ws;
  size_t off = 0;
  auto alloc = [&](size_t bytes)->void*{
    void* p = ws + off; off += (bytes + 255) & ~(size_t)255; return p;
  };
  float* attp  = (float*)alloc(7360*4);            // numg[3520] dmg[3520] dag[320]
  float* alpha = (float*)alloc(3520*4);
  float* beta  = (float*)alloc(45056*4);
  float* mdash = (float*)alloc(327680*4);
  float* ybuf  = (float*)alloc(327680*4);
  float* xA    = (float*)alloc(327680*4);
  float* hb    = (float*)alloc(327680*4);
  float* gap   = (float*)alloc(4096*4);
  float* Cpart = (float*)alloc((size_t)8*983040*4);   // 31.5 MB, reused x3
  _Float16* Abuf = (_Float16*)alloc((size_t)5898240*2); // 11.8 MB, reused x3
  float* numg = attp, *dmg = attp+3520, *dag = attp+7040;

  // attention
  hipMemsetAsync(attp, 0, 7360*4, stream);
  k_alpha_part<<<dim3(44,8), 128, 0, stream>>>(outA, memory, numg, dmg, dag);
  k_cs_soft   <<<1, 320, 0, stream>>>(numg, dmg, dag, alpha);
  k_beta_f    <<<44, 256, 0, stream>>>(h_track, memory, beta);
  k_mdash     <<<4096, 128, 0, stream>>>(alpha, beta, memory, mdash);

  // conv1: temp = [out_enc | mdash], K=18432, N=1024, 16 splits x hs=18
  k_im2col<<<dim3(4,64), 256, 0, stream>>>(out_enc, Abuf, 18432, 0,    1024);
  k_im2col<<<dim3(4,64), 256, 0, stream>>>(mdash,   Abuf, 18432, 9216, 1024);
  k_gemm3<<<dim3(16,16), 512, 0, stream>>>(Abuf, w1, Cpart, 1024, 18432, 18432, 18, 16, 0);
  k_post_red<<<1280, 256, 0, stream>>>(Cpart, 16, b1, ybuf);

  // conv2: K=9216, N=1024, 16 splits x hs=9
  k_im2col<<<dim3(4,64), 256, 0, stream>>>(ybuf, Abuf, 9216, 0, 1024);
  k_gemm3<<<dim3(16,16), 512, 0, stream>>>(Abuf, w2, Cpart, 1024, 9216, 9216, 9, 16, 0);
  k_post_red<<<1280, 256, 0, stream>>>(Cpart, 16, b2, xA);

  // lstm conv: keep only i/o/g gates (48 of 64 n-tiles; f unused since h0=0)
  k_im2col<<<dim3(4,64), 256, 0, stream>>>(xA, Abuf, 9216, 0, 1024);
  k_gemm3<<<dim3(48,8), 512, 0, stream>>>(Abuf, wl, Cpart, 3072, 9216, 18432, 18, 16, 16);
  k_lstm_red<<<1280, 256, 0, stream>>>(Cpart, bl, hb);

  // head
  k_gap<<<16, 256, 0, stream>>>(hb, gap);
  k_fc <<<1, 512, 0, stream>>>(gap, wfc, bfc, out);
}